// Round 7
// baseline (108.935 us; speedup 1.0000x reference)
//
#include <hip/hip_runtime.h>
#include <math.h>

#define EPSQ 1e-8f
#define LOG2E 1.4426950408889634f

typedef float f2 __attribute__((ext_vector_type(2)));

__device__ __forceinline__ float rcp_fast(float x) { return __builtin_amdgcn_rcpf(x); }
__device__ __forceinline__ float rsq_fast(float x) { return __builtin_amdgcn_rsqf(x); }
__device__ __forceinline__ f2 pk_fma(f2 a, f2 b, f2 c) { return __builtin_elementwise_fma(a, b, c); }

// DPP cross-lane move: ctrl must be a compile-time constant.
#define DPP_F(x, ctrl) \
    __int_as_float(__builtin_amdgcn_update_dpp(0, __float_as_int(x), (ctrl), 0xF, 0xF, true))

// All-reduce sum within each 16-lane DPP row (pure VALU).
__device__ __forceinline__ float allsum16(float v) {
    v += DPP_F(v, 0xB1);   // quad_perm [1,0,3,2]  == xor 1
    v += DPP_F(v, 0x4E);   // quad_perm [2,3,0,1]  == xor 2
    v += DPP_F(v, 0x124);  // row_ror:4
    v += DPP_F(v, 0x128);  // row_ror:8
    return v;
}
// All-reduce sum across the 4 rows (lanes l, l^16, l^32, l^48) — LDS pipe.
__device__ __forceinline__ float allsum_rows(float v) {
    v += __shfl_xor(v, 16);
    v += __shfl_xor(v, 32);
    return v;
}

// ---- setup: fold scale into normalized quats, pre-arrange as operand-ready
// pk-pairs, lane-indexed for the main kernel. ws layout (float4):
//   ws[0..255]   = (m0|m1) = ( w, w, -x, x)
//   ws[256..511] = (m2|m3) = (-y, y, -z,-z)
//   ws[512..767] = T       = ( 0, tx, ty, tz)
// record t = k*64 + l, lane l = r*16+o (r=l>>4, o=l&15), i = 4k + r.
__global__ void setup_kernel(const float* __restrict__ quats,
                             const float* __restrict__ scale,
                             const float* __restrict__ trans,
                             float4* __restrict__ ws) {
    const int t = threadIdx.x;            // 0..255
    const int k = t >> 6, l = t & 63;
    const int r = l >> 4, o = l & 15;
    const int i = 4 * k + r;
    const int pidx = o * 16 + i;
    const float4 q = ((const float4*)quats)[pidx];     // (w,x,y,z)
    const float sc = scale[pidx];
    const float f = sc * rsq_fast(q.x*q.x + q.y*q.y + q.z*q.z + q.w*q.w + EPSQ);
    const float w = q.x * f, x = q.y * f, y = q.z * f, z = q.w * f;
    ws[t]       = make_float4( w,  w, -x,  x);
    ws[256 + t] = make_float4(-y,  y, -z, -z);
    ws[512 + t] = make_float4(0.f, trans[pidx*3+0], trans[pidx*3+1], trans[pidx*3+2]);
}

// ---- main: one WAVE per sample. Block = 256 = 4 waves = 4 samples.
// Lane l: o = l&15 (softmax dim, in-row -> DPP), r = l>>4 (i-subset owner).
// Thread holds votes for i in {r, r+4, r+8, r+12} -> 16 VGPRs of votes
// (vs 64 in the thread-per-(n,o) mapping) -> ~8 waves/SIMD occupancy.
__global__ __launch_bounds__(256, 4) void caps_kernel(
    const float*  __restrict__ x,     // [N,16,4]
    const float4* __restrict__ ws,    // folded param tables (768 float4)
    const float*  __restrict__ bias,  // [16]
    const float*  __restrict__ beta,  // [16]
    const float*  __restrict__ alpha, // [16]
    float* __restrict__ out)          // [N,16,4]
{
    __shared__ __align__(16) float4 tabA[256];  // (m0|m1), dense lane-indexed
    __shared__ __align__(16) float4 tabB[256];  // (m2|m3)
    __shared__ __align__(16) float4 tabC[256];  // T
    __shared__ __align__(16) float4 xs[64];     // x tile: 4 samples x 16 i
    __shared__ __align__(16) float4 xsw[64];    // pair-swapped copy (x,w,z,y)

    const int tid = threadIdx.x;
    tabA[tid] = ws[tid];
    tabB[tid] = ws[256 + tid];
    tabC[tid] = ws[512 + tid];
    if (tid < 64) {
        const float4 xv = ((const float4*)x)[(size_t)blockIdx.x * 64 + tid];
        xs[tid]  = xv;
        xsw[tid] = make_float4(xv.y, xv.x, xv.w, xv.z);
    }
    __syncthreads();

    const int w = tid >> 6;          // wave = sample within block
    const int l = tid & 63;
    const int r = l >> 4;            // row = i-subset
    const int o = l & 15;

    // ---- votes for i = 4k + r, k=0..3: guaranteed-clean pk_fma hamilton ----
    f2 vwx[4], vyz[4];
    #pragma unroll
    for (int k = 0; k < 4; ++k) {
        const int rec = k * 64 + l;
        const float4 A = tabA[rec];
        const float4 B = tabB[rec];
        const float4 C = tabC[rec];
        const int xi = w * 16 + 4 * k + r;
        const float4 xv = xs[xi];     // (w2,x2,y2,z2), broadcast over o-lanes
        const float4 xw = xsw[xi];    // (x2,w2,z2,y2)
        const f2 m0  = f2{A.x, A.y}, m1  = f2{A.z, A.w};
        const f2 m2  = f2{B.x, B.y}, m3  = f2{B.z, B.w};
        const f2 P0  = f2{xv.x, xv.y}, P1  = f2{xv.z, xv.w};
        const f2 P0s = f2{xw.x, xw.y}, P1s = f2{xw.z, xw.w};
        f2 a = pk_fma(m0, P0, f2{C.x, C.y});   // (vote.w, vote.x + tx)
        a = pk_fma(m1, P0s, a);
        a = pk_fma(m2, P1,  a);
        a = pk_fma(m3, P1s, a);
        f2 b2 = pk_fma(m0, P1, f2{C.z, C.w});  // (vote.y + ty, vote.z + tz)
        b2 = pk_fma(m1, P1s, b2);
        b2 = pk_fma(-m2, P0,  b2);             // whole-vector fneg -> neg modifier
        b2 = pk_fma(-m3, P0s, b2);
        vwx[k] = a; vyz[k] = b2;
    }

    // ---- routing iter 0: uniform c = 1/16, folded into squash ----
    f2 v0wx, v0yz, vlwx, vlyz;
    {
        f2 uwx = (vwx[0] + vwx[1]) + (vwx[2] + vwx[3]);
        f2 uyz = (vyz[0] + vyz[1]) + (vyz[2] + vyz[3]);
        uwx.x = allsum_rows(uwx.x); uwx.y = allsum_rows(uwx.y);
        uyz.x = allsum_rows(uyz.x); uyz.y = allsum_rows(uyz.y);
        f2 d = uwx * uwx; d = pk_fma(uyz, uyz, d);
        const float n2 = (d.x + d.y) * (1.0f / 256.0f);
        const float fq = n2 * rcp_fast(1.f + n2) * rsq_fast(n2 + EPSQ) * 0.0625f;
        v0wx = uwx * fq; v0yz = uyz * fq;
        vlwx = v0wx * LOG2E; vlyz = v0yz * LOG2E;
    }

    // ---- routing iters 1..2 ----
    // b recomputed from the running v-sum in log2 domain; softmax over o is
    // the in-row 4-DPP all-reduce (serves all 4 rows' i's per instruction).
    f2 s_wx, s_yz, vowx, voyz;
    #pragma unroll
    for (int it = 1; it < 3; ++it) {
        f2 snwx = f2{0.f, 0.f}, snyz = f2{0.f, 0.f};
        #pragma unroll
        for (int k = 0; k < 4; ++k) {
            f2 d2 = vlwx * vwx[k];
            d2 = pk_fma(vlyz, vyz[k], d2);
            const float e  = __builtin_amdgcn_exp2f(d2.x + d2.y);
            const float se = allsum16(e);           // over o (16-lane row)
            const float c  = e * rcp_fast(se);
            snwx = pk_fma(f2{c, c}, vwx[k], snwx);
            snyz = pk_fma(f2{c, c}, vyz[k], snyz);
        }
        // finish sum over i: cross-row reduce
        snwx.x = allsum_rows(snwx.x); snwx.y = allsum_rows(snwx.y);
        snyz.x = allsum_rows(snyz.x); snyz.y = allsum_rows(snyz.y);
        const float n2 = snwx.x*snwx.x + snwx.y*snwx.y + snyz.x*snyz.x + snyz.y*snyz.y;
        const float fq = n2 * rcp_fast(1.f + n2) * rsq_fast(n2 + EPSQ);
        vowx = snwx * fq; voyz = snyz * fq;
        s_wx = snwx; s_yz = snyz;
        if (it == 1) {   // generator for iter 2: log2e * (v0 + v1)
            vlwx = (v0wx + vowx) * LOG2E;
            vlyz = (v0yz + voyz) * LOG2E;
        }
    }

    // ---- activation + store (row 0 lanes store: 16 consecutive float4) ----
    const float n2f = s_wx.x*s_wx.x + s_wx.y*s_wx.y + s_yz.x*s_yz.x + s_yz.y*s_yz.y;
    const float norm_s = sqrtf(n2f + EPSQ);
    const float tgt = beta[o] * norm_s + alpha[o] + bias[o];
    const float aAct = rcp_fast(1.f + __builtin_amdgcn_exp2f(-tgt * LOG2E));
    if (r == 0) {
        float4 ov;
        ov.x = vowx.x * aAct; ov.y = vowx.y * aAct;
        ov.z = voyz.x * aAct; ov.w = voyz.y * aAct;
        ((float4*)out)[((size_t)blockIdx.x * 4 + w) * 16 + o] = ov;
    }
}

extern "C" void kernel_launch(void* const* d_in, const int* in_sizes, int n_in,
                              void* d_out, int out_size, void* d_ws, size_t ws_size,
                              hipStream_t stream) {
    const float* x     = (const float*)d_in[0];
    const float* quats = (const float*)d_in[1];
    const float* scale = (const float*)d_in[2];
    const float* trans = (const float*)d_in[3];
    const float* bias  = (const float*)d_in[4];
    const float* beta  = (const float*)d_in[5];
    const float* alpha = (const float*)d_in[6];
    float* out = (float*)d_out;
    float4* wsv = (float4*)d_ws;     // 768 float4 = 12 KB of scratch

    const int N = in_sizes[0] / 64;  // x is [N,16,4]
    setup_kernel<<<1, 256, 0, stream>>>(quats, scale, trans, wsv);
    caps_kernel<<<N / 4, 256, 0, stream>>>(x, wsv, bias, beta, alpha, out);
}

// Round 8
// 99.220 us; speedup vs baseline: 1.0979x; 1.0979x over previous
//
#include <hip/hip_runtime.h>
#include <math.h>

#define EPSQ 1e-8f
#define LOG2E 1.4426950408889634f
#define TILES_PER_BLOCK 4

typedef float f2 __attribute__((ext_vector_type(2)));

__device__ __forceinline__ float rcp_fast(float x) { return __builtin_amdgcn_rcpf(x); }
__device__ __forceinline__ float rsq_fast(float x) { return __builtin_amdgcn_rsqf(x); }
__device__ __forceinline__ f2 pk_fma(f2 a, f2 b, f2 c) { return __builtin_elementwise_fma(a, b, c); }

// DPP cross-lane move: ctrl must be a compile-time constant.
#define DPP_F(x, ctrl) \
    __int_as_float(__builtin_amdgcn_update_dpp(0, __float_as_int(x), (ctrl), 0xF, 0xF, true))

// All-reduce sum within each aligned 16-lane group (pure VALU, no LDS).
__device__ __forceinline__ float allsum16(float v) {
    v += DPP_F(v, 0xB1);   // quad_perm [1,0,3,2]  == xor 1
    v += DPP_F(v, 0x4E);   // quad_perm [2,3,0,1]  == xor 2
    v += DPP_F(v, 0x124);  // row_ror:4
    v += DPP_F(v, 0x128);  // row_ror:8
    return v;
}

// One thread per (sample n, output capsule o). Block = 256 = 16 samples x 16 o.
// tid = ln*16 + o (o in low 4 bits): softmax-over-o lives in one 16-lane DPP row.
// Grid-stride over TILES_PER_BLOCK tiles: params staged ONCE per block, x tile
// double-buffered (prefetch overlaps compute) -- attacks per-block startup
// latency, the only cost R6's 4096 single-tile blocks paid 4x for.
__global__ __launch_bounds__(256, 4) void caps_kernel(
    const float* __restrict__ x,      // [N,16,4]
    const float* __restrict__ quats,  // [16,16,4]
    const float* __restrict__ scale,  // [16,16,1]
    const float* __restrict__ trans,  // [16,16,3]
    const float* __restrict__ bias,   // [16]
    const float* __restrict__ beta,   // [16]
    const float* __restrict__ alpha,  // [16]
    float* __restrict__ out,          // [N,16,4]
    int tiles_total)
{
    __shared__ __align__(16) float qs[16][16][4];   // folded scale * qn  [i][o][4]
    __shared__ __align__(16) float tr[16][16][4];   // (0, tx, ty, tz)    [i][o][4]
    __shared__ __align__(16) float xs[2][16][68];   // x tiles, ping-pong, +4 pad

    const int tid = threadIdx.x;
    const int o   = tid & 15;
    const int ln  = tid >> 4;

    // ---- stage params ONCE per block (o2 in low bits: LDS write addrs 16B
    // apart within a 16-lane group -> 2-way bank aliasing (free)).
    {
        const int o2 = tid & 15, i2 = tid >> 4;
        const int pidx = o2 * 16 + i2;                    // [o2][i2] entry
        const float4 q = ((const float4*)quats)[pidx];
        const float sc = scale[pidx];
        const float qn2 = q.x*q.x + q.y*q.y + q.z*q.z + q.w*q.w;
        const float f = sc * rsq_fast(qn2 + EPSQ);
        qs[i2][o2][0] = q.x * f;
        qs[i2][o2][1] = q.y * f;
        qs[i2][o2][2] = q.z * f;
        qs[i2][o2][3] = q.w * f;
        tr[i2][o2][0] = 0.0f;                 // real part untranslated
        tr[i2][o2][1] = trans[pidx*3 + 0];
        tr[i2][o2][2] = trans[pidx*3 + 1];
        tr[i2][o2][3] = trans[pidx*3 + 2];
    }
    // per-o epilogue constants, hoisted out of the tile loop
    const float beta_o = beta[o];
    const float ab_o   = alpha[o] + bias[o];

    // ---- prefetch tile 0 and stage into buffer 0 ----
    size_t tile = blockIdx.x;
    {
        const float4 xv = ((const float4*)x)[tile * 256 + tid];
        *(float4*)&xs[0][tid >> 4][(tid & 15) * 4] = xv;
    }
    __syncthreads();

    #pragma unroll
    for (int t = 0; t < TILES_PER_BLOCK; ++t) {
        // issue next tile's global load; it stays in flight during compute
        float4 xnext;
        const size_t ntile = tile + gridDim.x;
        if (t < TILES_PER_BLOCK - 1)
            xnext = ((const float4*)x)[ntile * 256 + tid];

        const int buf = t & 1;

        // ---- votes[i] = (scale*qn) (x) x[n,i] + trans, packed fp32 pairs --
        f2 vwx[16], vyz[16];
        #pragma unroll
        for (int i = 0; i < 16; ++i) {
            const float4 q4 = *(const float4*)&qs[i][o][0];
            const float4 t4 = *(const float4*)&tr[i][o][0];
            const float4 x4 = *(const float4*)&xs[buf][ln][i * 4];
            f2 a, b2;
            // (qw*xw - qx*xx - qy*xy - qz*xz , qw*xx + qx*xw + qy*xz - qz*xy) + (0,tx)
            a = pk_fma(f2{ q4.x,  q4.x}, f2{x4.x, x4.y}, f2{t4.x, t4.y});
            a = pk_fma(f2{-q4.y,  q4.y}, f2{x4.y, x4.x}, a);
            a = pk_fma(f2{-q4.z,  q4.z}, f2{x4.z, x4.w}, a);
            a = pk_fma(f2{-q4.w, -q4.w}, f2{x4.w, x4.z}, a);
            // (qw*xy - qx*xz + qy*xw + qz*xx , qw*xz + qx*xy - qy*xx + qz*xw) + (ty,tz)
            b2 = pk_fma(f2{ q4.x,  q4.x}, f2{x4.z, x4.w}, f2{t4.z, t4.w});
            b2 = pk_fma(f2{-q4.y,  q4.y}, f2{x4.w, x4.z}, b2);
            b2 = pk_fma(f2{ q4.z, -q4.z}, f2{x4.x, x4.y}, b2);
            b2 = pk_fma(f2{ q4.w,  q4.w}, f2{x4.y, x4.x}, b2);
            vwx[i] = a; vyz[i] = b2;
        }

        // Running log2-domain logit generator: b_i = dot(vl, votes_i).
        f2 vlwx, vlyz, v0wx, v0yz;

        // ---- routing iter 0: b==0 -> uniform c=1/16, folded into squash ----
        {
            f2 uwx = f2{0.f, 0.f}, uyz = f2{0.f, 0.f};
            #pragma unroll
            for (int i = 0; i < 16; ++i) { uwx += vwx[i]; uyz += vyz[i]; }
            f2 d = uwx * uwx;
            d = pk_fma(uyz, uyz, d);
            const float n2 = (d.x + d.y) * (1.0f / 256.0f);
            const float fq = n2 * rcp_fast(1.f + n2) * rsq_fast(n2 + EPSQ) * 0.0625f;
            v0wx = uwx * fq; v0yz = uyz * fq;
            vlwx = v0wx * LOG2E; vlyz = v0yz * LOG2E;
        }

        // ---- routing iters 1..2: softmax over o via DPP all-reduce.
        // Max-subtraction dropped: |b_log2| bounded -> exp2 never overflows.
        f2 s_wx, s_yz, vowx, voyz;
        #pragma unroll
        for (int it = 1; it < 3; ++it) {
            f2 snwx = f2{0.f, 0.f}, snyz = f2{0.f, 0.f};
            #pragma unroll
            for (int i = 0; i < 16; ++i) {
                f2 d2 = vlwx * vwx[i];
                d2 = pk_fma(vlyz, vyz[i], d2);
                const float e  = __builtin_amdgcn_exp2f(d2.x + d2.y);
                const float se = allsum16(e);
                const float c  = e * rcp_fast(se);
                snwx = pk_fma(f2{c, c}, vwx[i], snwx);
                snyz = pk_fma(f2{c, c}, vyz[i], snyz);
            }
            s_wx = snwx; s_yz = snyz;
            const float n2 = snwx.x*snwx.x + snwx.y*snwx.y + snyz.x*snyz.x + snyz.y*snyz.y;
            const float fq = n2 * rcp_fast(1.f + n2) * rsq_fast(n2 + EPSQ);
            vowx = snwx * fq; voyz = snyz * fq;
            if (it == 1) {   // generator for iter 2: log2e * (v0 + v1)
                vlwx = (v0wx + vowx) * LOG2E;
                vlyz = (v0yz + voyz) * LOG2E;
            }
        }

        // ---- activation + store (coalesced float4 per thread) ----
        const float n2f = s_wx.x*s_wx.x + s_wx.y*s_wx.y + s_yz.x*s_yz.x + s_yz.y*s_yz.y;
        const float norm_s = sqrtf(n2f + EPSQ);
        const float tgt = beta_o * norm_s + ab_o;
        const float aAct = rcp_fast(1.f + __builtin_amdgcn_exp2f(-tgt * LOG2E));
        float4 ov;
        ov.x = vowx.x * aAct; ov.y = vowx.y * aAct;
        ov.z = voyz.x * aAct; ov.w = voyz.y * aAct;
        ((float4*)out)[tile * 256 + tid] = ov;

        // ---- stage next tile into the other buffer; barrier gates reuse ----
        if (t < TILES_PER_BLOCK - 1) {
            *(float4*)&xs[buf ^ 1][tid >> 4][(tid & 15) * 4] = xnext;
            __syncthreads();
            tile = ntile;
        }
    }
}

extern "C" void kernel_launch(void* const* d_in, const int* in_sizes, int n_in,
                              void* d_out, int out_size, void* d_ws, size_t ws_size,
                              hipStream_t stream) {
    const float* x     = (const float*)d_in[0];
    const float* quats = (const float*)d_in[1];
    const float* scale = (const float*)d_in[2];
    const float* trans = (const float*)d_in[3];
    const float* bias  = (const float*)d_in[4];
    const float* beta  = (const float*)d_in[5];
    const float* alpha = (const float*)d_in[6];
    float* out = (float*)d_out;

    const int N = in_sizes[0] / 64;              // x is [N,16,4]
    const int tiles = N / 16;                    // 4096
    const int grid = tiles / TILES_PER_BLOCK;    // 1024 blocks, 4 tiles each
    caps_kernel<<<grid, 256, 0, stream>>>(x, quats, scale, trans, bias, beta, alpha,
                                          out, tiles);
}

// Round 9
// 97.427 us; speedup vs baseline: 1.1181x; 1.0184x over previous
//
#include <hip/hip_runtime.h>
#include <math.h>

#define EPSQ 1e-8f
#define LOG2E 1.4426950408889634f

typedef float f2 __attribute__((ext_vector_type(2)));
typedef float f4 __attribute__((ext_vector_type(4)));

__device__ __forceinline__ float rcp_fast(float x) { return __builtin_amdgcn_rcpf(x); }
__device__ __forceinline__ float rsq_fast(float x) { return __builtin_amdgcn_rsqf(x); }
__device__ __forceinline__ f2 pk_fma(f2 a, f2 b, f2 c) { return __builtin_elementwise_fma(a, b, c); }

// DPP cross-lane move: ctrl must be a compile-time constant.
#define DPP_F(x, ctrl) \
    __int_as_float(__builtin_amdgcn_update_dpp(0, __float_as_int(x), (ctrl), 0xF, 0xF, true))

// All-reduce sum within each aligned 16-lane group (pure VALU, no LDS).
__device__ __forceinline__ float allsum16(float v) {
    v += DPP_F(v, 0xB1);   // quad_perm [1,0,3,2]  == xor 1
    v += DPP_F(v, 0x4E);   // quad_perm [2,3,0,1]  == xor 2
    v += DPP_F(v, 0x124);  // row_ror:4
    v += DPP_F(v, 0x128);  // row_ror:8
    return v;
}

// Hamilton product (q * x) + t as EXACTLY 8 v_pk_fma_f32: all broadcasts,
// swaps, and sign patterns live in VOP3P op_sel/neg modifiers, so the
// compiler cannot expand them into v_mov/v_xor operand-prep.
//   q01=(w,x) q23=(y,z)  p01=(xw,xx) p23=(xy,xz)  ta=(0,tx) tb=(ty,tz)
//   a  = (vote.w, vote.x+tx)   b2 = (vote.y+ty, vote.z+tz)
__device__ __forceinline__ void hamilton_pk(f2 q01, f2 q23, f2 p01, f2 p23,
                                            f2 ta, f2 tb, f2& a, f2& b2) {
    asm("v_pk_fma_f32 %0, %2, %3, %4 op_sel:[0,0,0] op_sel_hi:[0,1,1]\n\t"                           // a  = (w,w)*(xw,xx) + ta
        "v_pk_fma_f32 %0, %2, %3, %0 op_sel:[1,1,0] op_sel_hi:[1,0,1] neg_lo:[1,0,0]\n\t"            // a += (-x,x)*(xx,xw)
        "v_pk_fma_f32 %0, %5, %6, %0 op_sel:[0,0,0] op_sel_hi:[0,1,1] neg_lo:[1,0,0]\n\t"            // a += (-y,y)*(xy,xz)
        "v_pk_fma_f32 %0, %5, %6, %0 op_sel:[1,1,0] op_sel_hi:[1,0,1] neg_lo:[1,0,0] neg_hi:[1,0,0]\n\t" // a += (-z,-z)*(xz,xy)
        "v_pk_fma_f32 %1, %2, %6, %7 op_sel:[0,0,0] op_sel_hi:[0,1,1]\n\t"                           // b  = (w,w)*(xy,xz) + tb
        "v_pk_fma_f32 %1, %2, %6, %1 op_sel:[1,1,0] op_sel_hi:[1,0,1] neg_lo:[1,0,0]\n\t"            // b += (-x,x)*(xz,xy)
        "v_pk_fma_f32 %1, %5, %3, %1 op_sel:[0,0,0] op_sel_hi:[0,1,1] neg_hi:[1,0,0]\n\t"            // b += (y,-y)*(xw,xx)
        "v_pk_fma_f32 %1, %5, %3, %1 op_sel:[1,1,0] op_sel_hi:[1,0,1]"                               // b += (z,z)*(xx,xw)
        : "=&v"(a), "=&v"(b2)
        : "v"(q01), "v"(p01), "v"(ta), "v"(q23), "v"(p23), "v"(tb));
}

// One thread per (sample n, output capsule o). Block = 256 = 16 samples x 16 o.
// tid = ln*16 + o (o in low 4 bits): softmax-over-o lives in one 16-lane DPP row.
__global__ __launch_bounds__(256, 4) void caps_kernel(
    const float* __restrict__ x,      // [N,16,4]
    const float* __restrict__ quats,  // [16,16,4]
    const float* __restrict__ scale,  // [16,16,1]
    const float* __restrict__ trans,  // [16,16,3]
    const float* __restrict__ bias,   // [16]
    const float* __restrict__ beta,   // [16]
    const float* __restrict__ alpha,  // [16]
    float* __restrict__ out)          // [N,16,4]
{
    __shared__ __align__(16) float qs[16][16][4];  // folded scale * qn  [i][o][4]
    __shared__ __align__(16) float tr[16][16][4];  // (0, tx, ty, tz)    [i][o][4]
    __shared__ __align__(16) float xs[16][68];     // x tile, +4 float row pad

    const int tid = threadIdx.x;
    const int o   = tid & 15;
    const int ln  = tid >> 4;

    // ---- stage params (o2 in low bits: LDS write addrs 16B apart within a
    // 16-lane group -> 2-way bank aliasing (free), vs 16-way for i2-major).
    {
        const int o2 = tid & 15, i2 = tid >> 4;
        const int pidx = o2 * 16 + i2;                    // [o2][i2] entry
        const float4 q = ((const float4*)quats)[pidx];
        const float sc = scale[pidx];
        const float qn2 = q.x*q.x + q.y*q.y + q.z*q.z + q.w*q.w;
        const float f = sc * rsq_fast(qn2 + EPSQ);
        qs[i2][o2][0] = q.x * f;
        qs[i2][o2][1] = q.y * f;
        qs[i2][o2][2] = q.z * f;
        qs[i2][o2][3] = q.w * f;
        tr[i2][o2][0] = 0.0f;                 // real part untranslated
        tr[i2][o2][1] = trans[pidx*3 + 0];
        tr[i2][o2][2] = trans[pidx*3 + 1];
        tr[i2][o2][3] = trans[pidx*3 + 2];
    }
    // ---- stage x tile: 1024 contiguous floats, one float4 per thread ----
    {
        const float4 xv = ((const float4*)x)[(size_t)blockIdx.x * 256 + tid];
        *(float4*)&xs[tid >> 4][(tid & 15) * 4] = xv;
    }
    __syncthreads();

    // ---- votes[i] = (scale*qn) (x) x[n,i] + trans: 8 pk_fma each, via asm --
    f2 vwx[16], vyz[16];
    #pragma unroll
    for (int i = 0; i < 16; ++i) {
        const f4 q4 = *(const f4*)&qs[i][o][0];
        const f4 t4 = *(const f4*)&tr[i][o][0];
        const f4 x4 = *(const f4*)&xs[ln][i * 4];
        hamilton_pk(q4.lo, q4.hi, x4.lo, x4.hi, t4.lo, t4.hi, vwx[i], vyz[i]);
    }

    // Running log2-domain logit generator: b_i = dot(vl, votes_i), where
    // vl = log2e*v0 (iter 1), log2e*(v0+v1) (iter 2).
    f2 vlwx, vlyz, v0wx, v0yz;

    // ---- routing iter 0: b==0 -> uniform c=1/16, folded into squash ----
    {
        f2 uwx = f2{0.f, 0.f}, uyz = f2{0.f, 0.f};
        #pragma unroll
        for (int i = 0; i < 16; ++i) { uwx += vwx[i]; uyz += vyz[i]; }
        f2 d = uwx * uwx;
        d = pk_fma(uyz, uyz, d);
        const float n2 = (d.x + d.y) * (1.0f / 256.0f);
        const float fq = n2 * rcp_fast(1.f + n2) * rsq_fast(n2 + EPSQ) * 0.0625f;
        v0wx = uwx * fq; v0yz = uyz * fq;
        vlwx = v0wx * LOG2E; vlyz = v0yz * LOG2E;
    }

    // ---- routing iters 1..2: softmax over o via DPP all-reduce.
    // Max-subtraction dropped: |b_log2| bounded -> exp2 never overflows fp32.
    f2 s_wx, s_yz, vowx, voyz;
    #pragma unroll
    for (int it = 1; it < 3; ++it) {
        f2 snwx = f2{0.f, 0.f}, snyz = f2{0.f, 0.f};
        #pragma unroll
        for (int i = 0; i < 16; ++i) {
            f2 d2 = vlwx * vwx[i];
            d2 = pk_fma(vlyz, vyz[i], d2);
            const float e  = __builtin_amdgcn_exp2f(d2.x + d2.y);
            const float se = allsum16(e);
            const float c  = e * rcp_fast(se);
            snwx = pk_fma(f2{c, c}, vwx[i], snwx);
            snyz = pk_fma(f2{c, c}, vyz[i], snyz);
        }
        s_wx = snwx; s_yz = snyz;
        const float n2 = snwx.x*snwx.x + snwx.y*snwx.y + snyz.x*snyz.x + snyz.y*snyz.y;
        const float fq = n2 * rcp_fast(1.f + n2) * rsq_fast(n2 + EPSQ);
        vowx = snwx * fq; voyz = snyz * fq;
        if (it == 1) {   // generator for iter 2: log2e * (v0 + v1)
            vlwx = (v0wx + vowx) * LOG2E;
            vlyz = (v0yz + voyz) * LOG2E;
        }
    }

    // ---- activation + store (coalesced float4 per thread) ----
    const float n2f = s_wx.x*s_wx.x + s_wx.y*s_wx.y + s_yz.x*s_yz.x + s_yz.y*s_yz.y;
    const float norm_s = sqrtf(n2f + EPSQ);
    const float tgt = beta[o] * norm_s + alpha[o] + bias[o];
    const float aAct = rcp_fast(1.f + __builtin_amdgcn_exp2f(-tgt * LOG2E));
    float4 ov;
    ov.x = vowx.x * aAct; ov.y = vowx.y * aAct;
    ov.z = voyz.x * aAct; ov.w = voyz.y * aAct;
    ((float4*)out)[(size_t)blockIdx.x * 256 + tid] = ov;
}

extern "C" void kernel_launch(void* const* d_in, const int* in_sizes, int n_in,
                              void* d_out, int out_size, void* d_ws, size_t ws_size,
                              hipStream_t stream) {
    const float* x     = (const float*)d_in[0];
    const float* quats = (const float*)d_in[1];
    const float* scale = (const float*)d_in[2];
    const float* trans = (const float*)d_in[3];
    const float* bias  = (const float*)d_in[4];
    const float* beta  = (const float*)d_in[5];
    const float* alpha = (const float*)d_in[6];
    float* out = (float*)d_out;

    const int N = in_sizes[0] / 64;      // x is [N,16,4]
    caps_kernel<<<N / 16, 256, 0, stream>>>(x, quats, scale, trans, bias, beta, alpha, out);
}